// Round 7
// baseline (679.384 us; speedup 1.0000x reference)
//
#include <hip/hip_runtime.h>
#include <hip/hip_bf16.h>
#include <math.h>

#define H 128
#define LOG2E 1.44269504f

typedef _Float16 f16;
typedef _Float16 f16x2 __attribute__((ext_vector_type(2)));
typedef _Float16 f16x8 __attribute__((ext_vector_type(8)));
typedef float f32x4 __attribute__((ext_vector_type(4)));
typedef float f32x2 __attribute__((ext_vector_type(2)));
typedef unsigned int uint32;

union u2h { uint32 u; f16x2 h; };
static __device__ __forceinline__ f16x2 as_h2(uint32 v){ u2h x; x.u = v; return x.h; }
static __device__ __forceinline__ uint32 pack_h2(float a, float b){
  u2h p; p.h = (f16x2){(f16)a, (f16)b}; return p.u;
}

// ---------------------------------------------------------------------------
// R17 layout (all-FP16): PT[node][1024] f16, LT[node][512] f16.
// SRC regions pair-packed: {f[2m],f[2m+1],s[2m],s[2m+1]} per uint2.
// DST regions pair-packed per relation-part block.
// RBF nearest-bin table T2: 256 bins, same pair-packing, L2-resident.
// ALL f/s ingredients pre-scaled by LOG2E (exp2-based activation); softplus
// ln2 folded into BN weight product (BN_SCL).
// Node state: SINGLE f16 array per entity (feeds f16 MFMA directly).
// node_update: wave handles TWO perm-adjacent nodes; B's setup loads are
// prefetched before A's aggregation (hides setup latency under pipeline).
// CSR edge info packed as int2 {src, float_bits(d)}.
// ---------------------------------------------------------------------------
static __device__ __forceinline__ int unperm64(int r){
  int base = r & ~63; int g = r & 63; int t = g >> 4; int j = g & 15;
  return base + 4*j + t;
}

#define NBIN 256
#define PREP_WP_N (4*1024*128)
#define PREP_WL_N (4*512*128)
#define RBF_N     (12*(NBIN+1)*128)
#define FC_N      (32*128)

__global__ void prep_all(const float* __restrict__ Wf, const float* __restrict__ Ws,
                         const float* __restrict__ bfv, const float* __restrict__ bsv,
                         f16* __restrict__ Wt_p, float* __restrict__ Bias_p,
                         f16* __restrict__ Wt_l, float* __restrict__ Bias_l,
                         f16* __restrict__ T2,
                         const float* __restrict__ fcw,
                         f16* __restrict__ fwhi, f16* __restrict__ fwlo,
                         const float* __restrict__ Xp, const float* __restrict__ Wp,
                         const float* __restrict__ bp, f16* __restrict__ Xph, int NP,
                         const float* __restrict__ Xl, const float* __restrict__ Wl,
                         const float* __restrict__ bl, f16* __restrict__ Xlh, int NL){
  int t = blockIdx.x*blockDim.x + threadIdx.x;
  if (t < PREP_WP_N){
    int k = t & 127; int idx = t >> 7;
    int rs = idx & 1023; int l = idx >> 10;
    int r = unperm64(rs);
    int rel, c, row0; const float* W; float bias = 0.f;
    if (r < 512){
      rel = (r < 256) ? 0 : 2;
      int rr = r & 255; int j = rr & 3;
      W = (j >= 2) ? Ws : Wf;
      c = ((rr >> 2) << 1) | (j & 1);
      row0 = 128;
    }
    else if (r < 640) { rel=0; c=r-512; row0=0; W=Wf; bias = bfv[(l*3+rel)*H+c]; }
    else if (r < 768) { rel=0; c=r-640; row0=0; W=Ws; bias = bsv[(l*3+rel)*H+c]; }
    else if (r < 896) { rel=1; c=r-768; row0=0; W=Wf; bias = bfv[(l*3+rel)*H+c]; }
    else              { rel=1; c=r-896; row0=0; W=Ws; bias = bsv[(l*3+rel)*H+c]; }
    Wt_p[t] = (f16)(LOG2E * W[((size_t)(l*3+rel)*272 + row0 + k)*H + c]);
    if (k == 0) Bias_p[l*1024 + r] = LOG2E * bias;
    return;
  }
  t -= PREP_WP_N;
  if (t < PREP_WL_N){
    int k = t & 127; int idx = t >> 7;
    int rs = idx & 511; int l = idx >> 9;
    int r = unperm64(rs);
    int rel, c, row0; const float* W; float bias = 0.f;
    if (r < 256){
      rel = 1; int j = r & 3;
      W = (j >= 2) ? Ws : Wf;
      c = ((r >> 2) << 1) | (j & 1);
      row0 = 128;
    }
    else if (r < 384) { rel=2; c=r-256; row0=0; W=Wf; bias = bfv[(l*3+rel)*H+c]; }
    else              { rel=2; c=r-384; row0=0; W=Ws; bias = bsv[(l*3+rel)*H+c]; }
    Wt_l[t] = (f16)(LOG2E * W[((size_t)(l*3+rel)*272 + row0 + k)*H + c]);
    if (k == 0) Bias_l[l*512 + r] = LOG2E * bias;
    return;
  }
  t -= PREP_WL_N;
  if (t < RBF_N){
    int c = t & 127;
    int b = (t >> 7) % (NBIN+1);
    int pr = t / ((NBIN+1)*128);
    float d0 = (float)b * (8.0f/(float)NBIN);
    const float* wf = Wf + ((size_t)pr*272 + 256)*H + c;
    const float* ws = Ws + ((size_t)pr*272 + 256)*H + c;
    float f0=0.f, s0=0.f;
    #pragma unroll
    for (int k=0;k<16;k++){
      float o = 0.533333333f*(float)k;
      float tt = d0 - o;
      float r0 = __expf(-1.7578125f*tt*tt);
      f0 += r0*wf[(size_t)k*H]; s0 += r0*ws[(size_t)k*H];
    }
    f16* o = T2 + ((size_t)(pr*(NBIN+1) + b))*256;
    int m = c >> 1, sub = c & 1;
    o[4*m + sub]     = (f16)(LOG2E * f0);
    o[4*m + 2 + sub] = (f16)(LOG2E * s0);
    return;
  }
  t -= RBF_N;
  if (t < FC_N){
    int col = t >> 7, k = t & 127;
    float w = (col < 21) ? fcw[k*21 + col] : 0.f;
    f16 hi = (f16)w;
    fwhi[col*128 + k] = hi;
    fwlo[col*128 + k] = (f16)(w - (float)hi);
    return;
  }
  t -= FC_N;
  { // embeddings -> f16 state
    int idx = t;
    const float* Xin; const float* W; const float* b; f16* Xh;
    if (idx < NP*H){ Xin=Xp; W=Wp; b=bp; Xh=Xph; }
    else { idx -= NP*H; if (idx >= NL*H) return; Xin=Xl; W=Wl; b=bl; Xh=Xlh; }
    int n = idx >> 7, c = idx & 127;
    float acc = b[c];
    #pragma unroll
    for (int k=0;k<6;k++) acc += Xin[n*6+k] * W[k*H+c];
    Xh[idx] = (f16)acc;
  }
}

// ---------------------------------------------------------------------------
// CSR build: hist -> chunk sums -> mid scan -> final scan -> fill
// ---------------------------------------------------------------------------
__global__ void hist3_k(const int* __restrict__ dpp, int Epp,
                        const int* __restrict__ dlp, int Elp,
                        const int* __restrict__ dpl, int Epl,
                        int* __restrict__ cpp, int* __restrict__ clp, int* __restrict__ cpl){
  int e = blockIdx.x*blockDim.x + threadIdx.x;
  if (e < Epp) atomicAdd(&cpp[dpp[e]], 1);
  else if (e < Epp+Elp) atomicAdd(&clp[dlp[e-Epp]], 1);
  else if (e < Epp+Elp+Epl) atomicAdd(&cpl[dpl[e-Epp-Elp]], 1);
}

#define SCH 1024   // scan chunk size

__global__ void __launch_bounds__(256) chunksum_k(
    const int* __restrict__ counts, int NP, int NL, int Cpp, int Cpl,
    int* __restrict__ chsum){
  __shared__ int wred[4];
  int b = blockIdx.x;
  const int* cnt; int n; int ch;
  if (b < Cpp){ cnt = counts; n = NP; ch = b; }
  else if (b < 2*Cpp){ cnt = counts + NP; n = NP; ch = b - Cpp; }
  else { cnt = counts + 2*NP; n = NL; ch = b - 2*Cpp; }
  int base = ch * SCH;
  int tid = threadIdx.x;
  int s = 0;
  #pragma unroll
  for (int j=0;j<SCH/256;j++){
    int i = base + tid + j*256;
    if (i < n) s += cnt[i];
  }
  #pragma unroll
  for (int o=32;o>=1;o>>=1) s += __shfl_xor(s,o,64);
  if ((tid & 63) == 0) wred[tid>>6] = s;
  __syncthreads();
  if (tid == 0) chsum[b] = wred[0]+wred[1]+wred[2]+wred[3];
}

__global__ void __launch_bounds__(192) scanmid_k(
    int* __restrict__ chsum, int Cpp, int Cpl, int NP, int NL,
    int* __restrict__ rp_pp, int* __restrict__ rp_lp, int* __restrict__ rp_pl){
  int wid = threadIdx.x >> 6, lane = threadIdx.x & 63;
  int C, off; int* rp_end; int n;
  if (wid == 0){ C = Cpp; off = 0;      rp_end = rp_pp; n = NP; }
  else if (wid == 1){ C = Cpp; off = Cpp; rp_end = rp_lp; n = NP; }
  else { C = Cpl; off = 2*Cpp; rp_end = rp_pl; n = NL; }
  int v = (lane < C) ? chsum[off + lane] : 0;
  int x = v;
  #pragma unroll
  for (int o=1;o<64;o<<=1){
    int y = __shfl_up(x, o, 64);
    if (lane >= o) x += y;
  }
  if (lane < C) chsum[off + lane] = x - v;
  if (lane == 63) rp_end[n] = x;
}

__global__ void __launch_bounds__(1024) scanfin_k(
    const int* __restrict__ counts, int NP, int NL, int Cpp, int Cpl,
    const int* __restrict__ chsum,
    int* __restrict__ rp_pp, int* __restrict__ cur_pp,
    int* __restrict__ rp_lp, int* __restrict__ cur_lp,
    int* __restrict__ rp_pl, int* __restrict__ cur_pl){
  __shared__ int wsum[16];
  int b = blockIdx.x;
  const int* cnt; int n, ch; int* rp; int* cur;
  if (b < Cpp){ cnt = counts; n = NP; ch = b; rp = rp_pp; cur = cur_pp; }
  else if (b < 2*Cpp){ cnt = counts + NP; n = NP; ch = b - Cpp; rp = rp_lp; cur = cur_lp; }
  else { cnt = counts + 2*NP; n = NL; ch = b - 2*Cpp; rp = rp_pl; cur = cur_pl; }
  int tid = threadIdx.x, lane = tid & 63, wid = tid >> 6;
  int i = ch*SCH + tid;
  int v = (i < n) ? cnt[i] : 0;
  int x = v;
  #pragma unroll
  for (int o=1;o<64;o<<=1){
    int y = __shfl_up(x, o, 64);
    if (lane >= o) x += y;
  }
  if (lane == 63) wsum[wid] = x;
  __syncthreads();
  if (wid == 0 && lane < 16){
    int w = wsum[lane];
    #pragma unroll
    for (int o=1;o<16;o<<=1){
      int y = __shfl_up(w, o, 64);
      if (lane >= o) w += y;
    }
    wsum[lane] = w;
  }
  __syncthreads();
  int waveoff = (wid == 0) ? 0 : wsum[wid-1];
  int ex = chsum[b] + waveoff + x - v;
  if (i < n){ rp[i] = ex; cur[i] = ex; }
}

// fill packed int2 {src, d_bits}
__global__ void fill3_k(const int* __restrict__ ei_pp, const float* __restrict__ ea_pp, int Epp,
                        const int* __restrict__ ei_lp, const float* __restrict__ ea_lp, int Elp,
                        const int* __restrict__ ei_pl, const float* __restrict__ ea_pl, int Epl,
                        int* __restrict__ cur_pp, int2* __restrict__ e2_pp,
                        int* __restrict__ cur_lp, int2* __restrict__ e2_lp,
                        int* __restrict__ cur_pl, int2* __restrict__ e2_pl){
  int e = blockIdx.x*blockDim.x + threadIdx.x;
  if (e < Epp){
    int p = atomicAdd(&cur_pp[ei_pp[Epp + e]], 1);
    e2_pp[p] = make_int2(ei_pp[e], __float_as_int(ea_pp[e]));
  } else if (e < Epp+Elp){
    int i = e - Epp;
    int p = atomicAdd(&cur_lp[ei_lp[Elp + i]], 1);
    e2_lp[p] = make_int2(ei_lp[i], __float_as_int(ea_lp[i]));
  } else if (e < Epp+Elp+Epl){
    int i = e - Epp - Elp;
    int p = atomicAdd(&cur_pl[ei_pl[Epl + i]], 1);
    e2_pl[p] = make_int2(ei_pl[i], __float_as_int(ea_pl[i]));
  }
}

// ---------------------------------------------------------------------------
// Degree-balance sort (R12): 64-bin DESC counting sort of nodes by degree.
// ---------------------------------------------------------------------------
__global__ void __launch_bounds__(256) degbin_hist(
    const int* __restrict__ rp_pp, const int* __restrict__ rp_lp,
    const int* __restrict__ rp_pl, int NP, int NL, int* __restrict__ hist){
  __shared__ int lh[128];
  int t = threadIdx.x;
  if (t < 128) lh[t] = 0;
  __syncthreads();
  int i = blockIdx.x*256 + t;
  if (i < NP){
    int d = (rp_pp[i+1]-rp_pp[i]) + (rp_lp[i+1]-rp_lp[i]);
    if (d > 63) d = 63;
    atomicAdd(&lh[63 - d], 1);
  } else if (i < NP+NL){
    int n = i - NP;
    int d = rp_pl[n+1]-rp_pl[n];
    if (d > 63) d = 63;
    atomicAdd(&lh[64 + 63 - d], 1);
  }
  __syncthreads();
  if (t < 128 && lh[t]) atomicAdd(&hist[t], lh[t]);
}

__global__ void __launch_bounds__(128) degbin_scan(
    const int* __restrict__ hist, int* __restrict__ cursor){
  int t = threadIdx.x, lane = t & 63;
  int v = hist[t];
  int x = v;
  #pragma unroll
  for (int o=1;o<64;o<<=1){
    int y = __shfl_up(x, o, 64);
    if (lane >= o) x += y;
  }
  cursor[t] = x - v;   // exclusive prefix within segment
}

__global__ void __launch_bounds__(256) degbin_scatter(
    const int* __restrict__ rp_pp, const int* __restrict__ rp_lp,
    const int* __restrict__ rp_pl, int NP, int NL,
    int* __restrict__ cursor, int* __restrict__ perm){
  __shared__ int lh[128], lbase[128], lrank[128];
  int t = threadIdx.x;
  if (t < 128){ lh[t] = 0; lrank[t] = 0; }
  __syncthreads();
  int i = blockIdx.x*256 + t;
  int bin = -1, n = 0;
  if (i < NP){
    n = i;
    int d = (rp_pp[i+1]-rp_pp[i]) + (rp_lp[i+1]-rp_lp[i]);
    if (d > 63) d = 63;
    bin = 63 - d;
  } else if (i < NP+NL){
    n = i - NP;
    int d = rp_pl[n+1]-rp_pl[n];
    if (d > 63) d = 63;
    bin = 64 + 63 - d;
  }
  if (bin >= 0) atomicAdd(&lh[bin], 1);
  __syncthreads();
  if (t < 128 && lh[t]) lbase[t] = atomicAdd(&cursor[t], lh[t]);
  __syncthreads();
  if (bin >= 0){
    int r = atomicAdd(&lrank[bin], 1);
    perm[(bin < 64 ? 0 : NP) + lbase[bin] + r] = n;
  }
}

// ---------------------------------------------------------------------------
// Table GEMM (B-resident, f16 MFMA) with XCD-chunk task remap (R16).
// ---------------------------------------------------------------------------
#define GR 8
__global__ void __launch_bounds__(256) gemm_tables(
    const f16* __restrict__ Xp, const f16* __restrict__ Wtp,
    const float* __restrict__ Biasp, f16* __restrict__ Outp,
    int strips_p, int chunks_p, int pblocks,
    const f16* __restrict__ Xl, const f16* __restrict__ Wtl,
    const float* __restrict__ Biasl, f16* __restrict__ Outl,
    int strips_l, int chunks_l){
  int b = blockIdx.x;
  int w = threadIdx.x >> 6;
  const f16 *X, *Wt; const float* Bias; f16* Out; int N, strips, g, chunk;
  if (b < pblocks){
    int c = (b >> 5)*8 + (b & 7);
    if (c >= chunks_p) return;
    X=Xp; Wt=Wtp; Bias=Biasp; Out=Outp; N=1024; strips=strips_p;
    g = ((b >> 3) & 3)*4 + w; chunk = c;
  } else {
    int bl = b - pblocks;
    int c = (bl >> 4)*8 + (bl & 7);
    if (c >= chunks_l) return;
    X=Xl; Wt=Wtl; Bias=Biasl; Out=Outl; N=512; strips=strips_l;
    g = ((bl >> 3) & 1)*4 + w; chunk = c;
  }
  int n0 = g << 6;
  int lane = threadIdx.x & 63;
  int lr = lane & 15, lq = lane >> 4;
  const f16x8* B0 = (const f16x8*)(const void*)(Wt + (size_t)(n0      + lr)*H);
  const f16x8* B1 = (const f16x8*)(const void*)(Wt + (size_t)(n0 + 16 + lr)*H);
  const f16x8* B2 = (const f16x8*)(const void*)(Wt + (size_t)(n0 + 32 + lr)*H);
  const f16x8* B3 = (const f16x8*)(const void*)(Wt + (size_t)(n0 + 48 + lr)*H);
  f16x8 b0_0=B0[lq], b0_1=B0[4+lq], b0_2=B0[8+lq], b0_3=B0[12+lq];
  f16x8 b1_0=B1[lq], b1_1=B1[4+lq], b1_2=B1[8+lq], b1_3=B1[12+lq];
  f16x8 b2_0=B2[lq], b2_1=B2[4+lq], b2_2=B2[8+lq], b2_3=B2[12+lq];
  f16x8 b3_0=B3[lq], b3_1=B3[4+lq], b3_2=B3[8+lq], b3_3=B3[12+lq];
  float4 bias = ((const float4*)(const void*)(Bias + n0))[lr];
  #pragma unroll 2
  for (int r=0;r<GR;r++){
    int strip = chunk*GR + r;
    if (strip >= strips) break;
    int m0 = strip << 4;
    const f16x8* A = (const f16x8*)(const void*)(X + (size_t)(m0+lr)*H);
    f16x8 a0 = A[lq], a1 = A[4+lq], a2 = A[8+lq], a3 = A[12+lq];
    f32x4 acc0 = {0.f,0.f,0.f,0.f}, acc1 = acc0, acc2 = acc0, acc3 = acc0;
    acc0 = __builtin_amdgcn_mfma_f32_16x16x32_f16(a0, b0_0, acc0, 0, 0, 0);
    acc1 = __builtin_amdgcn_mfma_f32_16x16x32_f16(a0, b1_0, acc1, 0, 0, 0);
    acc2 = __builtin_amdgcn_mfma_f32_16x16x32_f16(a0, b2_0, acc2, 0, 0, 0);
    acc3 = __builtin_amdgcn_mfma_f32_16x16x32_f16(a0, b3_0, acc3, 0, 0, 0);
    acc0 = __builtin_amdgcn_mfma_f32_16x16x32_f16(a1, b0_1, acc0, 0, 0, 0);
    acc1 = __builtin_amdgcn_mfma_f32_16x16x32_f16(a1, b1_1, acc1, 0, 0, 0);
    acc2 = __builtin_amdgcn_mfma_f32_16x16x32_f16(a1, b2_1, acc2, 0, 0, 0);
    acc3 = __builtin_amdgcn_mfma_f32_16x16x32_f16(a1, b3_1, acc3, 0, 0, 0);
    acc0 = __builtin_amdgcn_mfma_f32_16x16x32_f16(a2, b0_2, acc0, 0, 0, 0);
    acc1 = __builtin_amdgcn_mfma_f32_16x16x32_f16(a2, b1_2, acc1, 0, 0, 0);
    acc2 = __builtin_amdgcn_mfma_f32_16x16x32_f16(a2, b2_2, acc2, 0, 0, 0);
    acc3 = __builtin_amdgcn_mfma_f32_16x16x32_f16(a2, b3_2, acc3, 0, 0, 0);
    acc0 = __builtin_amdgcn_mfma_f32_16x16x32_f16(a3, b0_3, acc0, 0, 0, 0);
    acc1 = __builtin_amdgcn_mfma_f32_16x16x32_f16(a3, b1_3, acc1, 0, 0, 0);
    acc2 = __builtin_amdgcn_mfma_f32_16x16x32_f16(a3, b2_3, acc2, 0, 0, 0);
    acc3 = __builtin_amdgcn_mfma_f32_16x16x32_f16(a3, b3_3, acc3, 0, 0, 0);
    #pragma unroll
    for (int rr=0;rr<4;rr++){
      int row = m0 + lq*4 + rr;
      uint2 pk;
      pk.x = pack_h2(acc0[rr] + bias.x, acc1[rr] + bias.y);
      pk.y = pack_h2(acc2[rr] + bias.z, acc3[rr] + bias.w);
      *(uint2*)(void*)(Out + (size_t)row*N + n0 + 4*lr) = pk;
    }
  }
}

// ---------------------------------------------------------------------------
// Node-update helpers (inputs pre-scaled by LOG2E; softplus ln2 folded into
// BN weight product)
// ---------------------------------------------------------------------------
static __device__ __forceinline__ float act_msg(float F, float S){
  float sig = __builtin_amdgcn_rcpf(1.f + __builtin_amdgcn_exp2f(-F));
  float e   = __builtin_amdgcn_exp2f(fminf(S, 86.f));
  return sig * __builtin_amdgcn_logf(1.f + e);   // ln2 applied via BN_SCL
}

#define BN_SCL (0.9999950000374997f * 0.69314718f)  /* ln2 / sqrt(1+1e-5) */

// pair-packed edge kernel: g.x/t.x = f-pair (h2), g.y/t.y = s-pair (h2)
static __device__ __forceinline__ void edge_nb(uint2 g, uint2 t,
                                               f16x2 fd2, f16x2 sd2, f32x2& acc){
  f16x2 F = (as_h2(g.x) + as_h2(t.x)) + fd2;   // v_pk_add_f16 x2
  f16x2 S = (as_h2(g.y) + as_h2(t.y)) + sd2;   // v_pk_add_f16 x2
  acc.x += act_msg((float)F.x, (float)S.x);
  acc.y += act_msg((float)F.y, (float)S.y);
}

static __device__ __forceinline__ void ln_stats_w(float v0, float v1, float& mu, float& var){
  float s = v0 + v1, q = v0*v0 + v1*v1;
  #pragma unroll
  for (int o=32;o>=1;o>>=1){ s += __shfl_xor(s,o,64); q += __shfl_xor(q,o,64); }
  mu = s * (1.f/128.f);
  var = q * (1.f/128.f) - mu*mu;
}

// CSR aggregation: 64-edge chunk of {src,bin} in registers; per edge
// 2 readlane (SALU) + 2 gathers. Rotation-free 3-stage modulo schedule
// (R2 form — the only schedule that holds; R1/R3 variants regressed).
static __device__ __forceinline__ void aggregate(
    const int2* __restrict__ ev_arr, int e0, int e1,
    const uint2* __restrict__ G, int gstride, int goff,
    const uint2* __restrict__ Tb, int lane,
    f16x2 fd2, f16x2 sd2, f32x2& acc)
{
  for (int base = e0; base < e1; base += 64){
    int idx = base + lane;
    int2 ev = ev_arr[(idx < e1) ? idx : (e1-1)];
    float dd = __int_as_float(ev.y);
    int bnv = (int)__fmaf_rn(dd, (float)NBIN/8.0f, 0.5f);
    bnv = (bnv > NBIN) ? NBIN : bnv;
    int cnt = e1 - base; cnt = (cnt > 64) ? 64 : cnt;
    uint2 gA, tA, gB, tB, gC, tC;
    #define LDJ(gX, tX, j) { \
      int s_ = __builtin_amdgcn_readlane(ev.x, (j)); \
      int b_ = __builtin_amdgcn_readlane(bnv, (j)); \
      gX = G[(size_t)s_*gstride + goff + lane]; \
      tX = Tb[(size_t)b_*64 + lane]; }
    LDJ(gA, tA, 0);
    if (cnt > 1) LDJ(gB, tB, 1);
    if (cnt > 2) LDJ(gC, tC, 2);
    int j = 0;
    for (; j+5 < cnt; j += 3){
      edge_nb(gA, tA, fd2, sd2, acc); LDJ(gA, tA, j+3);
      edge_nb(gB, tB, fd2, sd2, acc); LDJ(gB, tB, j+4);
      edge_nb(gC, tC, fd2, sd2, acc); LDJ(gC, tC, j+5);
    }
    int rem = cnt - j;              // 1..5
    edge_nb(gA, tA, fd2, sd2, acc);
    if (rem > 3) LDJ(gA, tA, j+3);
    if (rem > 1) edge_nb(gB, tB, fd2, sd2, acc);
    if (rem > 4) LDJ(gB, tB, j+4);
    if (rem > 2) edge_nb(gC, tC, fd2, sd2, acc);
    if (rem > 3) edge_nb(gA, tA, fd2, sd2, acc);
    if (rem > 4) edge_nb(gB, tB, fd2, sd2, acc);
    #undef LDJ
  }
}

// relation post-processing: BN (pre-folded) + residual + LN + relu + residual
static __device__ __forceinline__ void rel_post(
    f32x2 acc, float2 bwf, float2 bb, float2 lw, float2 lb,
    float xx, float xy, float& o0, float& o1)
{
  float v0 = acc.x * bwf.x + bb.x + xx;
  float v1 = acc.y * bwf.y + bb.y + xy;
  float mu, var; ln_stats_w(v0, v1, mu, var);
  float rs = rsqrtf(var + 1e-5f);
  o0 = fmaxf((v0-mu)*rs*lw.x + lb.x, 0.f) + xx;
  o1 = fmaxf((v1-mu)*rs*lw.y + lb.y, 0.f) + xy;
}

// ---------------------------------------------------------------------------
// Merged node update (R17): wave handles TWO perm-adjacent nodes (equal
// degree via sort). Node B's x/dst loads are issued BEFORE node A's
// aggregation so B's setup latency hides under A's pipeline. LN/BN params
// loaded once per wave. 2-wave blocks. Blocks [0,PB) protein, rest ligand.
// ---------------------------------------------------------------------------
__global__ void __launch_bounds__(128) node_update(
    const f16* __restrict__ PT, const f16* __restrict__ LT,
    const f16* __restrict__ xp, const f16* __restrict__ xl,
    const int* __restrict__ pp_rp, const int2* __restrict__ pp_e2,
    const int* __restrict__ lp_rp, const int2* __restrict__ lp_e2,
    const int* __restrict__ pl_rp, const int2* __restrict__ pl_e2,
    const f16* __restrict__ T2,
    const float* __restrict__ bn_w, const float* __restrict__ bn_b,
    const float* __restrict__ ln_w, const float* __restrict__ ln_b,
    const int* __restrict__ perm,
    f16* __restrict__ xp_o, f16* __restrict__ xl_o,
    int layer, int NP, int NL, int PB)
{
  int wave = threadIdx.x >> 6;
  int lane = threadIdx.x & 63;
  const uint2* PTg = (const uint2*)(const void*)PT;
  if ((int)blockIdx.x < PB){
    int idx0 = blockIdx.x*4 + wave*2;
    if (idx0 >= NP) return;
    const uint32* PTu = (const uint32*)(const void*)PT;
    const uint2*  LTg = (const uint2*)(const void*)LT;
    const uint32* Xu  = (const uint32*)(const void*)xp;
    uint32* Xo = (uint32*)(void*)xp_o;
    int pr0 = layer*3, pr1 = layer*3 + 1;
    const uint2* Tb0 = (const uint2*)(const void*)(T2 + (size_t)pr0*(NBIN+1)*256);
    const uint2* Tb1 = (const uint2*)(const void*)(T2 + (size_t)pr1*(NBIN+1)*256);
    // per-wave params (shared across both nodes)
    float2 bw0 = ((const float2*)(const void*)(bn_w + pr0*H))[lane];
    float2 bb0 = ((const float2*)(const void*)(bn_b + pr0*H))[lane];
    float2 lw0 = ((const float2*)(const void*)(ln_w + pr0*H))[lane];
    float2 lb0 = ((const float2*)(const void*)(ln_b + pr0*H))[lane];
    float2 bw1 = ((const float2*)(const void*)(bn_w + pr1*H))[lane];
    float2 bb1 = ((const float2*)(const void*)(bn_b + pr1*H))[lane];
    float2 lw1 = ((const float2*)(const void*)(ln_w + pr1*H))[lane];
    float2 lb1 = ((const float2*)(const void*)(ln_b + pr1*H))[lane];
    bw0.x *= BN_SCL; bw0.y *= BN_SCL; bw1.x *= BN_SCL; bw1.y *= BN_SCL;
    int nodeA = perm[idx0];
    bool hasB = (idx0 + 1 < NP);
    int nodeB = perm[hasB ? (idx0 + 1) : idx0];
    // CSR ranges (A and B) early
    int a_pp0 = pp_rp[nodeA], a_pp1 = pp_rp[nodeA+1];
    int a_lp0 = lp_rp[nodeA], a_lp1 = lp_rp[nodeA+1];
    int b_pp0 = pp_rp[nodeB], b_pp1 = pp_rp[nodeB+1];
    int b_lp0 = lp_rp[nodeB], b_lp1 = lp_rp[nodeB+1];
    // prefetch node B setup (hides under A's aggregation)
    uint32 xBu  = Xu[(size_t)nodeB*64 + lane];
    uint32 fdB0 = PTu[(size_t)nodeB*512 + 256 + lane];
    uint32 sdB0 = PTu[(size_t)nodeB*512 + 320 + lane];
    uint32 fdB1 = PTu[(size_t)nodeB*512 + 384 + lane];
    uint32 sdB1 = PTu[(size_t)nodeB*512 + 448 + lane];
    // node A setup
    uint32 xAu  = Xu[(size_t)nodeA*64 + lane];
    uint32 fdA0 = PTu[(size_t)nodeA*512 + 256 + lane];
    uint32 sdA0 = PTu[(size_t)nodeA*512 + 320 + lane];
    uint32 fdA1 = PTu[(size_t)nodeA*512 + 384 + lane];
    uint32 sdA1 = PTu[(size_t)nodeA*512 + 448 + lane];
    { // ---- node A ----
      f16x2 xh = as_h2(xAu);
      float xx = (float)xh.x, xy = (float)xh.y;
      f32x2 acc0 = {0.f,0.f}, acc1 = {0.f,0.f};
      aggregate(pp_e2, a_pp0, a_pp1, PTg, 256, 0, Tb0, lane, as_h2(fdA0), as_h2(sdA0), acc0);
      aggregate(lp_e2, a_lp0, a_lp1, LTg, 128, 0, Tb1, lane, as_h2(fdA1), as_h2(sdA1), acc1);
      float o1_0, o1_1, o2_0, o2_1;
      rel_post(acc0, bw0, bb0, lw0, lb0, xx, xy, o1_0, o1_1);
      rel_post(acc1, bw1, bb1, lw1, lb1, xx, xy, o2_0, o2_1);
      Xo[(size_t)nodeA*64 + lane] = pack_h2(o1_0 + o2_0, o1_1 + o2_1);
    }
    if (hasB){ // ---- node B ----
      f16x2 xh = as_h2(xBu);
      float xx = (float)xh.x, xy = (float)xh.y;
      f32x2 acc0 = {0.f,0.f}, acc1 = {0.f,0.f};
      aggregate(pp_e2, b_pp0, b_pp1, PTg, 256, 0, Tb0, lane, as_h2(fdB0), as_h2(sdB0), acc0);
      aggregate(lp_e2, b_lp0, b_lp1, LTg, 128, 0, Tb1, lane, as_h2(fdB1), as_h2(sdB1), acc1);
      float o1_0, o1_1, o2_0, o2_1;
      rel_post(acc0, bw0, bb0, lw0, lb0, xx, xy, o1_0, o1_1);
      rel_post(acc1, bw1, bb1, lw1, lb1, xx, xy, o2_0, o2_1);
      Xo[(size_t)nodeB*64 + lane] = pack_h2(o1_0 + o2_0, o1_1 + o2_1);
    }
  } else {
    int idx0 = (blockIdx.x - PB)*4 + wave*2;
    if (idx0 >= NL) return;
    const uint32* LTu = (const uint32*)(const void*)LT;
    const uint32* Xu  = (const uint32*)(const void*)xl;
    uint32* Xo = (uint32*)(void*)xl_o;
    int pr2 = layer*3 + 2;
    const uint2* Tb2 = (const uint2*)(const void*)(T2 + (size_t)pr2*(NBIN+1)*256);
    float2 bw2 = ((const float2*)(const void*)(bn_w + pr2*H))[lane];
    float2 bb2 = ((const float2*)(const void*)(bn_b + pr2*H))[lane];
    float2 lw2 = ((const float2*)(const void*)(ln_w + pr2*H))[lane];
    float2 lb2 = ((const float2*)(const void*)(ln_b + pr2*H))[lane];
    bw2.x *= BN_SCL; bw2.y *= BN_SCL;
    int nodeA = perm[NP + idx0];
    bool hasB = (idx0 + 1 < NL);
    int nodeB = perm[NP + (hasB ? (idx0 + 1) : idx0)];
    int a_e0 = pl_rp[nodeA], a_e1 = pl_rp[nodeA+1];
    int b_e0 = pl_rp[nodeB], b_e1 = pl_rp[nodeB+1];
    uint32 xBu  = Xu[(size_t)nodeB*64 + lane];
    uint32 fdB2 = LTu[(size_t)nodeB*256 + 128 + lane];
    uint32 sdB2 = LTu[(size_t)nodeB*256 + 192 + lane];
    uint32 xAu  = Xu[(size_t)nodeA*64 + lane];
    uint32 fdA2 = LTu[(size_t)nodeA*256 + 128 + lane];
    uint32 sdA2 = LTu[(size_t)nodeA*256 + 192 + lane];
    { // node A
      f16x2 xh = as_h2(xAu);
      float xx = (float)xh.x, xy = (float)xh.y;
      f32x2 acc = {0.f,0.f};
      aggregate(pl_e2, a_e0, a_e1, PTg, 256, 64, Tb2, lane, as_h2(fdA2), as_h2(sdA2), acc);
      float o0, o1;
      rel_post(acc, bw2, bb2, lw2, lb2, xx, xy, o0, o1);
      Xo[(size_t)nodeA*64 + lane] = pack_h2(o0, o1);
    }
    if (hasB){
      f16x2 xh = as_h2(xBu);
      float xx = (float)xh.x, xy = (float)xh.y;
      f32x2 acc = {0.f,0.f};
      aggregate(pl_e2, b_e0, b_e1, PTg, 256, 64, Tb2, lane, as_h2(fdB2), as_h2(sdB2), acc);
      float o0, o1;
      rel_post(acc, bw2, bb2, lw2, lb2, xx, xy, o0, o1);
      Xo[(size_t)nodeB*64 + lane] = pack_h2(o0, o1);
    }
  }
}

// ---------------------------------------------------------------------------
// Final head (R15): out = LN(xp) @ fc_w + fc_b via MFMA, hi/lo split operands.
// ---------------------------------------------------------------------------
__global__ void __launch_bounds__(256) final_k(const f16* __restrict__ xp,
    const float* __restrict__ lnw, const float* __restrict__ lnb,
    const f16* __restrict__ fwhi, const f16* __restrict__ fwlo,
    const float* __restrict__ fcb, float* __restrict__ out, int N){
  int wave = threadIdx.x >> 6, lane = threadIdx.x & 63;
  int m0 = (blockIdx.x*4 + wave) << 4;
  if (m0 >= N) return;
  int lr = lane & 15, lq = lane >> 4;
  int node = m0 + lr; if (node >= N) node = N - 1;
  const f16x8* X = (const f16x8*)(const void*)(xp + (size_t)node*H);
  f16x8 x0 = X[lq], x1 = X[4+lq], x2 = X[8+lq], x3 = X[12+lq];
  float s = 0.f, q = 0.f;
  #pragma unroll
  for (int i=0;i<8;i++){
    float a=(float)x0[i], b=(float)x1[i], c=(float)x2[i], d=(float)x3[i];
    s += a+b+c+d; q += a*a+b*b+c*c+d*d;
  }
  s += __shfl_xor(s,16,64); q += __shfl_xor(q,16,64);
  s += __shfl_xor(s,32,64); q += __shfl_xor(q,32,64);
  float mu = s*(1.f/128.f), var = q*(1.f/128.f) - mu*mu;
  float rs = rsqrtf(var + 1e-5f);
  f16x8 xs0 = x0, xs1 = x1, xs2 = x2, xs3 = x3;
  f16x8 ah[4], al[4];
  const float4* LW = (const float4*)(const void*)lnw;
  const float4* LB = (const float4*)(const void*)lnb;
  #define MKFRAG(F, XS) { \
    int b4 = F*8 + lq*2; \
    float4 w0 = LW[b4], w1 = LW[b4+1]; \
    float4 c0 = LB[b4], c1 = LB[b4+1]; \
    float l0=((float)XS[0]-mu)*rs*w0.x + c0.x; \
    float l1=((float)XS[1]-mu)*rs*w0.y + c0.y; \
    float l2=((float)XS[2]-mu)*rs*w0.z + c0.z; \
    float l3=((float)XS[3]-mu)*rs*w0.w + c0.w; \
    float l4=((float)XS[4]-mu)*rs*w1.x + c1.x; \
    float l5=((float)XS[5]-mu)*rs*w1.y + c1.y; \
    float l6=((float)XS[6]-mu)*rs*w1.z + c1.z; \
    float l7=((float)XS[7]-mu)*rs*w1.w + c1.w; \
    f16x8 hh = {(f16)l0,(f16)l1,(f16)l2,(f16)l3,(f16)l4,(f16)l5,(f16)l6,(f16)l7}; \
    f16x8 ll = {(f16)(l0-(float)hh[0]),(f16)(l1-(float)hh[1]), \
                (f16)(l2-(float)hh[2]),(f16)(l3-(float)hh[3]), \
                (f16)(l4-(float)hh[4]),(f16)(l5-(float)hh[5]), \
                (f16)(l6-(float)hh[6]),(f16)(l7-(float)hh[7])}; \
    ah[F] = hh; al[F] = ll; }
  MKFRAG(0, xs0); MKFRAG(1, xs1); MKFRAG(2, xs2); MKFRAG(3, xs3);
  #undef MKFRAG
  const f16x8* BH0 = (const f16x8*)(const void*)(fwhi + (size_t)lr*128);
  const f16x8* BH1 = (const f16x8*)(const void*)(fwhi + (size_t)(16+lr)*128);
  const f16x8* BL0 = (const f16x8*)(const void*)(fwlo + (size_t)lr*128);
  const f16x8* BL1 = (const f16x8*)(const void*)(fwlo + (size_t)(16+lr)*128);
  f32x4 acc0 = {0.f,0.f,0.f,0.f}, acc1 = acc0;
  #pragma unroll
  for (int f=0; f<4; f++){
    f16x8 bh0 = BH0[f*4+lq], bh1 = BH1[f*4+lq];
    f16x8 bl0 = BL0[f*4+lq], bl1 = BL1[f*4+lq];
    acc0 = __builtin_amdgcn_mfma_f32_16x16x32_f16(ah[f], bh0, acc0, 0, 0, 0);
    acc1 = __builtin_amdgcn_mfma_f32_16x16x32_f16(ah[f], bh1, acc1, 0, 0, 0);
    acc0 = __builtin_amdgcn_mfma_f32_16x16x32_f16(al[f], bh0, acc0, 0, 0, 0);
    acc1 = __builtin_amdgcn_mfma_f32_16x16x32_f16(al[f], bh1, acc1, 0, 0, 0);
    acc0 = __builtin_amdgcn_mfma_f32_16x16x32_f16(ah[f], bl0, acc0, 0, 0, 0);
    acc1 = __builtin_amdgcn_mfma_f32_16x16x32_f16(ah[f], bl1, acc1, 0, 0, 0);
  }
  float bias0 = fcb[lr];
  float bias1 = (lr < 5) ? fcb[16 + lr] : 0.f;
  #pragma unroll
  for (int rr=0; rr<4; rr++){
    int row = m0 + lq*4 + rr;
    if (row < N){
      out[(size_t)row*21 + lr] = acc0[rr] + bias0;
      if (lr < 5) out[(size_t)row*21 + 16 + lr] = acc1[rr] + bias1;
    }
  }
}

// ---------------------------------------------------------------------------
extern "C" void kernel_launch(void* const* d_in, const int* in_sizes, int n_in,
                              void* d_out, int out_size, void* d_ws, size_t ws_size,
                              hipStream_t stream){
  const float* x_protein = (const float*)d_in[0];
  const float* x_ligand  = (const float*)d_in[1];
  const int*   ei_pp = (const int*)d_in[2];
  const float* ea_pp = (const float*)d_in[3];
  const int*   ei_lp = (const int*)d_in[4];
  const float* ea_lp = (const float*)d_in[5];
  const int*   ei_pl = (const int*)d_in[6];
  const float* ea_pl = (const float*)d_in[7];
  const float* Wp  = (const float*)d_in[8];
  const float* bp  = (const float*)d_in[9];
  const float* Wl  = (const float*)d_in[10];
  const float* bl  = (const float*)d_in[11];
  const float* Wf  = (const float*)d_in[12];
  const float* bfv = (const float*)d_in[13];
  const float* Wsv = (const float*)d_in[14];
  const float* bsv = (const float*)d_in[15];
  const float* bn_w = (const float*)d_in[16];
  const float* bn_b = (const float*)d_in[17];
  const float* ln_w = (const float*)d_in[18];
  const float* ln_b = (const float*)d_in[19];
  const float* lno_w = (const float*)d_in[20];
  const float* lno_b = (const float*)d_in[21];
  const float* fc_w = (const float*)d_in[22];
  const float* fc_b = (const float*)d_in[23];

  int NP  = in_sizes[0]/6, NL = in_sizes[1]/6;
  int EPP = in_sizes[3], ELP = in_sizes[5], EPL = in_sizes[7];

  char* ws = (char*)d_ws;
  size_t off = 0;
  auto alloc = [&](size_t bytes)->void*{
    void* p = ws + off; off = (off + bytes + 255) & ~(size_t)255; return p;
  };

  f16* xpA = (f16*)alloc((size_t)NP*H*2);
  f16* xpB = (f16*)alloc((size_t)NP*H*2);
  f16* xlA = (f16*)alloc((size_t)NL*H*2);
  f16* xlB = (f16*)alloc((size_t)NL*H*2);
  f16* PT    = (f16*)alloc((size_t)NP*1024*2);
  f16* LT    = (f16*)alloc((size_t)NL*512*2);
  f16* Wt_p  = (f16*)alloc((size_t)4*1024*H*2);
  f16* Wt_l  = (f16*)alloc((size_t)4*512*H*2);
  float* Bias_p = (float*)alloc((size_t)4*1024*4);
  float* Bias_l = (float*)alloc((size_t)4*512*4);
  f16* T2    = (f16*)alloc((size_t)12*(NBIN+1)*256*2);
  f16* fwhi  = (f16*)alloc((size_t)32*128*2);
  f16* fwlo  = (f16*)alloc((size_t)32*128*2);
  int* counts = (int*)alloc((size_t)(2*NP+NL)*4);
  int* rp_pp  = (int*)alloc((size_t)(NP+1)*4);
  int* cur_pp = (int*)alloc((size_t)NP*4);
  int* rp_lp  = (int*)alloc((size_t)(NP+1)*4);
  int* cur_lp = (int*)alloc((size_t)NP*4);
  int* rp_pl  = (int*)alloc((size_t)(NL+1)*4);
  int* cur_pl = (int*)alloc((size_t)NL*4);
  int2* e2_pp = (int2*)alloc((size_t)EPP*8);
  int2* e2_lp = (int2*)alloc((size_t)ELP*8);
  int2* e2_pl = (int2*)alloc((size_t)EPL*8);
  int Cpp = (NP + SCH - 1) / SCH;
  int Cpl = (NL + SCH - 1) / SCH;
  int* chsum = (int*)alloc((size_t)(2*Cpp + Cpl)*4);
  int* dhist  = (int*)alloc(128*4);
  int* dcur   = (int*)alloc(128*4);
  int* perm   = (int*)alloc((size_t)(NP+NL)*4);
  (void)ws_size; (void)n_in; (void)out_size;

  // --- prep (weights + RBF table + FC split + embeddings, one launch) ---
  size_t prep_total = (size_t)PREP_WP_N + PREP_WL_N + RBF_N + FC_N + (size_t)(NP+NL)*H;
  prep_all<<<(prep_total+255)/256, 256, 0, stream>>>(Wf, Wsv, bfv, bsv,
      Wt_p, Bias_p, Wt_l, Bias_l, T2,
      fc_w, fwhi, fwlo,
      x_protein, Wp, bp, xpA, NP,
      x_ligand,  Wl, bl, xlA, NL);
  // --- CSR build ---
  hipMemsetAsync(counts, 0, (size_t)(2*NP+NL)*4, stream);
  hipMemsetAsync(dhist, 0, 128*4, stream);
  int* cnt_pp = counts; int* cnt_lp = counts + NP; int* cnt_pl = counts + 2*NP;
  int Etot = EPP + ELP + EPL;
  hist3_k<<<(Etot+255)/256, 256, 0, stream>>>(ei_pp+EPP, EPP, ei_lp+ELP, ELP, ei_pl+EPL, EPL,
                                              cnt_pp, cnt_lp, cnt_pl);
  chunksum_k<<<2*Cpp + Cpl, 256, 0, stream>>>(counts, NP, NL, Cpp, Cpl, chsum);
  scanmid_k<<<1, 192, 0, stream>>>(chsum, Cpp, Cpl, NP, NL, rp_pp, rp_lp, rp_pl);
  scanfin_k<<<2*Cpp + Cpl, 1024, 0, stream>>>(counts, NP, NL, Cpp, Cpl, chsum,
                                              rp_pp, cur_pp, rp_lp, cur_lp, rp_pl, cur_pl);
  fill3_k<<<(Etot+255)/256, 256, 0, stream>>>(ei_pp, ea_pp, EPP, ei_lp, ea_lp, ELP,
                                              ei_pl, ea_pl, EPL,
                                              cur_pp, e2_pp, cur_lp, e2_lp, cur_pl, e2_pl);
  // --- degree-balance sort (needs rp arrays from scanfin_k) ---
  int nbks = (NP + NL + 255) / 256;
  degbin_hist<<<nbks, 256, 0, stream>>>(rp_pp, rp_lp, rp_pl, NP, NL, dhist);
  degbin_scan<<<1, 128, 0, stream>>>(dhist, dcur);
  degbin_scatter<<<nbks, 256, 0, stream>>>(rp_pp, rp_lp, rp_pl, NP, NL, dcur, perm);

  // --- layers ---
  f16* xp_cur = xpA; f16* xp_nxt = xpB;
  f16* xl_cur = xlA; f16* xl_nxt = xlB;
  int strips_p = NP >> 4, strips_l = NL >> 4;
  int chunks_p = (strips_p + GR - 1) / GR;
  int chunks_l = (strips_l + GR - 1) / GR;
  int pblocks = ((chunks_p + 7) / 8) * 32;   // 4 quads x 8 xcd-phases
  int lblocks = ((chunks_l + 7) / 8) * 16;   // 2 halves x 8 xcd-phases
  int PB = (NP + 3) / 4, LB = (NL + 3) / 4;  // 2 waves x 2 nodes per block
  for (int l=0; l<4; l++){
    gemm_tables<<<pblocks + lblocks, 256, 0, stream>>>(
        xp_cur, Wt_p + (size_t)l*1024*H, Bias_p + l*1024, PT, strips_p, chunks_p, pblocks,
        xl_cur, Wt_l + (size_t)l*512*H,  Bias_l + l*512,  LT, strips_l, chunks_l);
    node_update<<<PB + LB, 128, 0, stream>>>(PT, LT, xp_cur, xl_cur,
        rp_pp, e2_pp, rp_lp, e2_lp, rp_pl, e2_pl, T2,
        bn_w, bn_b, ln_w, ln_b, perm, xp_nxt, xl_nxt, l, NP, NL, PB);
    f16* t;
    t = xp_cur; xp_cur = xp_nxt; xp_nxt = t;
    t = xl_cur; xl_cur = xl_nxt; xl_nxt = t;
  }

  // --- output head (MFMA) ---
  int fstrips = (NP + 15) >> 4;
  final_k<<<(fstrips+3)/4, 256, 0, stream>>>(xp_cur, lno_w, lno_b,
      fwhi, fwlo, fc_b, (float*)d_out, NP);
}